// Round 1
// 727.722 us; speedup vs baseline: 1.0177x; 1.0177x over previous
//
#include <hip/hip_runtime.h>
#include <math.h>

#define NB 16
#define SL 2048
#define HD 64
#define TQ 16
#define BK 64
#define NT (SL / BK)          // 32 k-tiles
#define SC2 0.18033688f       // (1/TEMPERATURE) * log2(e): exp(s/8) = exp2(s*SC2)
#define SSTRIDE 2056          // fp16 elems per S row (2048 + 8 pad, 16B-aligned rows)

typedef _Float16 half8 __attribute__((ext_vector_type(8)));
typedef float floatx4 __attribute__((ext_vector_type(4)));
typedef int intx4 __attribute__((ext_vector_type(4)));

__device__ __forceinline__ half8 load_frag_f32(const float* p) {
  floatx4 f0 = *(const floatx4*)p;
  floatx4 f1 = *(const floatx4*)(p + 4);
  half8 h;
  h[0] = (_Float16)f0[0]; h[1] = (_Float16)f0[1];
  h[2] = (_Float16)f0[2]; h[3] = (_Float16)f0[3];
  h[4] = (_Float16)f1[0]; h[5] = (_Float16)f1[1];
  h[6] = (_Float16)f1[2]; h[7] = (_Float16)f1[3];
  return h;
}

// Pre-pass: K -> KH (f16, same [b][k][d] layout), V -> VT (f16, transposed [b][d][k]).
// Grid (SL/64, NB), 256 threads. Thread t: row r = t>>2, 16-col chunk cq = (t&3)*16.
__global__ __launch_bounds__(256) void prep_kernel(
    const float* __restrict__ K, const float* __restrict__ V,
    _Float16* __restrict__ KH, _Float16* __restrict__ VT)
{
  __shared__ __align__(16) _Float16 tile[64][72];   // V tile, 16-chunk XOR swizzle
  const int t  = (int)threadIdx.x;
  const int k0 = blockIdx.x * 64;
  const int b  = blockIdx.y;
  const size_t base = (size_t)b * SL * HD;
  const int r  = t >> 2;
  const int cq = (t & 3) * 16;

  const float* kp = K + base + (size_t)(k0 + r) * HD + cq;
  const float* vp = V + base + (size_t)(k0 + r) * HD + cq;
  half8 kh0 = load_frag_f32(kp), kh1 = load_frag_f32(kp + 8);
  half8 vh0 = load_frag_f32(vp), vh1 = load_frag_f32(vp + 8);

  _Float16* khp = KH + base + (size_t)(k0 + r) * HD + cq;
  *(half8*)khp       = kh0;
  *(half8*)(khp + 8) = kh1;

  // element (row,col) stored at tile[row][col ^ s(row)], s(row)=((row>>4)&3)*16
  const int wc = cq ^ (((r >> 4) & 3) * 16);        // r<16 -> s=0, but keep general
  *(half8*)&tile[r][wc]     = vh0;
  *(half8*)&tile[r][wc + 8] = vh1;
  __syncthreads();

  // write VT row d=r, k-chunk cq: gather column r of rows cq..cq+15 (swizzled read)
  const int sx = ((cq >> 4) & 3) * 16;
  half8 o0, o1;
  #pragma unroll
  for (int i = 0; i < 8; ++i) {
    o0[i] = tile[cq + i][r ^ sx];
    o1[i] = tile[cq + 8 + i][r ^ sx];
  }
  _Float16* vt = VT + (size_t)b * HD * SL + (size_t)r * SL + k0 + cq;
  *(half8*)vt       = o0;
  *(half8*)(vt + 8) = o1;
}

// One block = 16 q-rows of one batch, 512 threads = 8 waves, 2 blocks/CU (LDS-bound).
// Changes vs prior round: (1) all mask loads issued into registers BEFORE QK^T so the
// HBM mask stream overlaps the L2-bound MFMA phase; (2) K fragments from pre-converted
// f16 KH (half the L2 bytes, no cvt); (3) V fragments from pre-transposed f16 VT as two
// 16B vector loads instead of 16 scalar strided loads; (4) exp2 with folded log2e;
// (5) normalized attn stores interleaved into the PV loop (store drain hides under MFMA).
template <bool PREP>
__global__ __launch_bounds__(512) void attn_kernel(
    const float* __restrict__ Q, const float* __restrict__ K,
    const float* __restrict__ V, const _Float16* __restrict__ KH,
    const _Float16* __restrict__ VT, const int* __restrict__ DM,
    const int* __restrict__ MMk, float* __restrict__ Out,
    float* __restrict__ Attn)
{
  const int qt    = blockIdx.x;
  const int b     = blockIdx.y;
  const int tid   = (int)threadIdx.x;
  const int w     = tid >> 6;
  const int w4    = w & 3;
  const int hf    = w >> 2;
  const int lane  = tid & 63;
  const int quad  = lane >> 4;
  const int nl    = lane & 15;
  const int row16 = tid >> 5;
  const int ci    = tid & 31;

  const int qbase    = qt * TQ;
  const size_t bLD   = (size_t)b * SL * HD;
  const size_t mbase = ((size_t)b * SL + qbase) * SL;

  __shared__ __align__(16) _Float16 S[TQ * SSTRIDE];
  __shared__ float sinv_s[TQ];
  __shared__ float obuf[TQ][65];

  // ---- mask prefetch: all 8 chunks of this thread's row issued before QK^T ----
  // 32 intx4 = 128 VGPRs; occupancy is LDS-limited (2 blocks/CU needs <=512 VGPRs).
  const int* dmr = DM  + mbase + (size_t)row16 * SL;
  const int* mkr = MMk + mbase + (size_t)row16 * SL;
  intx4 pd0[8], pd1[8], pm0[8], pm1[8];
  #pragma unroll
  for (int it = 0; it < 8; ++it) {
    const int c = it * 256 + ci * 8;
    pd0[it] = __builtin_nontemporal_load((const intx4*)(dmr + c));
    pd1[it] = __builtin_nontemporal_load((const intx4*)(dmr + c + 4));
    pm0[it] = __builtin_nontemporal_load((const intx4*)(mkr + c));
    pm1[it] = __builtin_nontemporal_load((const intx4*)(mkr + c + 4));
  }

  // ---- Q fragments (A operand): lane holds Q[qbase + nl][quad*8+j (+32)]
  half8 aq0, aq1;
  {
    const float* qp = Q + bLD + (size_t)(qbase + nl) * HD + quad * 8;
    aq0 = load_frag_f32(qp);
    aq1 = load_frag_f32(qp + 32);
  }

  // ================= Phase A: QK^T -> S (each wave: 16 tiles) =================
  const int kt0 = hf * (NT / 2);
  #pragma unroll 2
  for (int kti = 0; kti < NT / 2; ++kti) {
    const int kt = kt0 + kti;
    half8 bk0, bk1;
    if constexpr (PREP) {
      const _Float16* kp = KH + bLD + (size_t)(kt * BK + w4 * 16 + nl) * HD + quad * 8;
      bk0 = *(const half8*)kp;
      bk1 = *(const half8*)(kp + 32);
    } else {
      const float* kp = K + bLD + (size_t)(kt * BK + w4 * 16 + nl) * HD + quad * 8;
      bk0 = load_frag_f32(kp);
      bk1 = load_frag_f32(kp + 32);
    }
    floatx4 acc = {0.f, 0.f, 0.f, 0.f};
    acc = __builtin_amdgcn_mfma_f32_16x16x32_f16(aq0, bk0, acc, 0, 0, 0);
    acc = __builtin_amdgcn_mfma_f32_16x16x32_f16(aq1, bk1, acc, 0, 0, 0);
    const int col = kt * BK + w4 * 16 + nl;
    #pragma unroll
    for (int r = 0; r < 4; ++r)
      S[(quad * 4 + r) * SSTRIDE + col] = (_Float16)(acc[r] * SC2);
  }
  __syncthreads();

  // ========== P1: mask+exp2+sum — mask data already in registers ==========
  _Float16* srow = &S[row16 * SSTRIDE];
  float sum = 0.f;
  #pragma unroll
  for (int it = 0; it < 8; ++it) {
    const int c = it * 256 + ci * 8;
    half8 s8 = *(const half8*)(srow + c);
    half8 e8;
    #pragma unroll
    for (int j = 0; j < 4; ++j) {
      const int keep0 = pd0[it][j] & ~pm0[it][j];   // d!=0 && m==0 (values are 0/1)
      const int keep1 = pd1[it][j] & ~pm1[it][j];
      const float e0 = keep0 ? __builtin_amdgcn_exp2f((float)s8[j])     : 0.f;
      const float e1 = keep1 ? __builtin_amdgcn_exp2f((float)s8[j + 4]) : 0.f;
      sum += e0 + e1;
      e8[j]     = (_Float16)e0;   // e <= ~e^6, fp16 safe (validated round 4)
      e8[j + 4] = (_Float16)e1;
    }
    *(half8*)(srow + c) = e8;     // unnormalized e for PV
  }
  #pragma unroll
  for (int off = 1; off < 32; off <<= 1)
    sum += __shfl_xor(sum, off, 64);   // 32 chunk-lanes of this row
  const float is = (sum > 0.f) ? 1.f / sum : 0.f;
  if (ci == 0) sinv_s[row16] = is;
  __syncthreads();   // all e in S + sinv_s visible before PV

  // ===== D2: PV MFMA (16 tiles/wave) with interleaved normalized attn stores =====
  const float isr = sinv_s[row16];
  float* arow = Attn + mbase + (size_t)row16 * SL;
  floatx4 oacc = {0.f, 0.f, 0.f, 0.f};
  #pragma unroll
  for (int kti = 0; kti < NT / 2; ++kti) {
    const int kt = kt0 + kti;
    // A operand: lane holds E[m = nl][k = kt*64 + quad*8 + j (+32)]
    half8 ap0 = *(const half8*)(&S[nl * SSTRIDE + kt * BK + quad * 8]);
    half8 ap1 = *(const half8*)(&S[nl * SSTRIDE + kt * BK + quad * 8 + 32]);
    // B operand: lane holds V[k = kt*64 + quad*8 + j (+32)][n = w4*16 + nl]
    half8 bv0, bv1;
    if constexpr (PREP) {
      const _Float16* vp = VT + bLD + (size_t)(w4 * 16 + nl) * SL + kt * BK + quad * 8;
      bv0 = *(const half8*)vp;
      bv1 = *(const half8*)(vp + 32);
    } else {
      const float* vp = V + bLD + (size_t)(kt * BK + quad * 8) * HD + w4 * 16 + nl;
      #pragma unroll
      for (int j = 0; j < 8; ++j) {
        bv0[j] = (_Float16)vp[(size_t)j * HD];
        bv1[j] = (_Float16)vp[(size_t)(j + 32) * HD];
      }
    }
    oacc = __builtin_amdgcn_mfma_f32_16x16x32_f16(ap0, bv0, oacc, 0, 0, 0);
    oacc = __builtin_amdgcn_mfma_f32_16x16x32_f16(ap1, bv1, oacc, 0, 0, 0);
    // P3 chunk every other tile: stores drain under the MFMA latency
    if ((kti & 1) == 0) {
      const int c = (kti >> 1) * 256 + ci * 8;
      half8 e8v = *(const half8*)(srow + c);
      floatx4 o0, o1;
      #pragma unroll
      for (int j = 0; j < 4; ++j) {
        o0[j] = (float)e8v[j]     * isr;
        o1[j] = (float)e8v[j + 4] * isr;
      }
      __builtin_nontemporal_store(o0, (floatx4*)(arow + c));
      __builtin_nontemporal_store(o1, (floatx4*)(arow + c + 4));
    }
  }

  // ---- merge the two k-halves, normalize, store O
  if (hf == 1) {
    #pragma unroll
    for (int r = 0; r < 4; ++r)
      obuf[quad * 4 + r][w4 * 16 + nl] = oacc[r];
  }
  __syncthreads();
  if (hf == 0) {
    float* op = Out + ((size_t)b * SL + qbase) * HD;
    #pragma unroll
    for (int r = 0; r < 4; ++r) {
      const int row = quad * 4 + r;
      op[(size_t)row * HD + w4 * 16 + nl] =
          (oacc[r] + obuf[row][w4 * 16 + nl]) * sinv_s[row];
    }
  }
}

extern "C" void kernel_launch(void* const* d_in, const int* in_sizes, int n_in,
                              void* d_out, int out_size, void* d_ws, size_t ws_size,
                              hipStream_t stream) {
  const float* Q  = (const float*)d_in[0];
  const float* K  = (const float*)d_in[1];
  const float* V  = (const float*)d_in[2];
  const int* DM   = (const int*)d_in[3];
  const int* MMk  = (const int*)d_in[4];
  float* Out  = (float*)d_out;
  float* Attn = (float*)d_out + (size_t)NB * SL * HD;
  dim3 grid(SL / TQ, NB);
  const size_t need = (size_t)2 * NB * SL * HD * sizeof(_Float16);  // KH + VT = 8 MiB
  if (d_ws != nullptr && ws_size >= need) {
    _Float16* KH = (_Float16*)d_ws;
    _Float16* VT = KH + (size_t)NB * SL * HD;
    prep_kernel<<<dim3(SL / 64, NB), 256, 0, stream>>>(K, V, KH, VT);
    attn_kernel<true><<<grid, 512, 0, stream>>>(Q, K, V, KH, VT, DM, MMk, Out, Attn);
  } else {
    // workspace too small: fall back to in-kernel conversion paths
    attn_kernel<false><<<grid, 512, 0, stream>>>(Q, K, V, nullptr, nullptr, DM, MMk, Out, Attn);
  }
}

// Round 2
// 696.297 us; speedup vs baseline: 1.0636x; 1.0451x over previous
//
#include <hip/hip_runtime.h>
#include <math.h>

#define NB 16
#define SL 2048
#define HD 64
#define TQ 16
#define BK 64
#define NT (SL / BK)          // 32 k-tiles
#define SC2 0.18033688f       // (1/TEMPERATURE) * log2(e): exp(s/8) = exp2(s*SC2)
#define SSTRIDE 2056          // fp16 elems per S row (2048 + 8 pad, 16B-aligned rows)

typedef _Float16 half8 __attribute__((ext_vector_type(8)));
typedef float floatx4 __attribute__((ext_vector_type(4)));
typedef int intx4 __attribute__((ext_vector_type(4)));

__device__ __forceinline__ half8 load_frag_f32(const float* p) {
  floatx4 f0 = *(const floatx4*)p;
  floatx4 f1 = *(const floatx4*)(p + 4);
  half8 h;
  h[0] = (_Float16)f0[0]; h[1] = (_Float16)f0[1];
  h[2] = (_Float16)f0[2]; h[3] = (_Float16)f0[3];
  h[4] = (_Float16)f1[0]; h[5] = (_Float16)f1[1];
  h[6] = (_Float16)f1[2]; h[7] = (_Float16)f1[3];
  return h;
}

// Fused pre-pass, 256 threads/block, grid.x = 2048 (pack) + 512 (prep).
// Pack part (first, so the big stream starts immediately): reads DM+MMk (512 MB,
// the only consumer of the raw masks), combines keep = dm & ~mk, bit-packs to
// BITS (8 MiB, 1 bit/element -> L2/L3 resident for the attn kernel).
// Prep part: K -> KH (f16), V -> VT (f16 transposed [b][d][k]).
__global__ __launch_bounds__(256) void prep_pack_kernel(
    const float* __restrict__ K, const float* __restrict__ V,
    const int* __restrict__ DM, const int* __restrict__ MMk,
    _Float16* __restrict__ KH, _Float16* __restrict__ VT,
    unsigned char* __restrict__ BITS)
{
  const int bid = blockIdx.x;
  const int t   = (int)threadIdx.x;

  if (bid < 2048) {
    // ---- pack: 16 rows per block, thread t covers cols [t*8, t*8+8) ----
    const size_t r0 = (size_t)bid * 16;
    #pragma unroll 4
    for (int r = 0; r < 16; ++r) {
      const size_t off = (r0 + r) * SL + (size_t)t * 8;
      intx4 d0 = __builtin_nontemporal_load((const intx4*)(DM + off));
      intx4 d1 = __builtin_nontemporal_load((const intx4*)(DM + off + 4));
      intx4 m0 = __builtin_nontemporal_load((const intx4*)(MMk + off));
      intx4 m1 = __builtin_nontemporal_load((const intx4*)(MMk + off + 4));
      unsigned byte = 0;
      #pragma unroll
      for (int j = 0; j < 4; ++j) {
        byte |= (unsigned)((d0[j] & ~m0[j]) & 1) << j;
        byte |= (unsigned)((d1[j] & ~m1[j]) & 1) << (j + 4);
      }
      BITS[(r0 + r) * (SL / 8) + t] = (unsigned char)byte;   // regular store: keep in L2/L3
    }
    return;
  }

  // ---- prep: K/V conversion, block handles 64 k-rows of one batch ----
  __shared__ __align__(16) _Float16 tile[64][72];   // V tile, 16-chunk XOR swizzle
  const int pb = bid - 2048;
  const int k0 = (pb & 31) * 64;
  const int b  = pb >> 5;
  const size_t base = (size_t)b * SL * HD;
  const int r  = t >> 2;
  const int cq = (t & 3) * 16;

  const float* kp = K + base + (size_t)(k0 + r) * HD + cq;
  const float* vp = V + base + (size_t)(k0 + r) * HD + cq;
  half8 kh0 = load_frag_f32(kp), kh1 = load_frag_f32(kp + 8);
  half8 vh0 = load_frag_f32(vp), vh1 = load_frag_f32(vp + 8);

  _Float16* khp = KH + base + (size_t)(k0 + r) * HD + cq;
  *(half8*)khp       = kh0;
  *(half8*)(khp + 8) = kh1;

  // element (row,col) stored at tile[row][col ^ s(row)], s(row)=((row>>4)&3)*16
  const int wc = cq ^ (((r >> 4) & 3) * 16);
  *(half8*)&tile[r][wc]     = vh0;
  *(half8*)&tile[r][wc + 8] = vh1;
  __syncthreads();

  const int sx = ((cq >> 4) & 3) * 16;
  half8 o0, o1;
  #pragma unroll
  for (int i = 0; i < 8; ++i) {
    o0[i] = tile[cq + i][r ^ sx];
    o1[i] = tile[cq + 8 + i][r ^ sx];
  }
  _Float16* vt = VT + (size_t)b * HD * SL + (size_t)r * SL + k0 + cq;
  *(half8*)vt       = o0;
  *(half8*)(vt + 8) = o1;
}

// One block = 16 q-rows of one batch, 512 threads = 8 waves.
// MODE 2: f16 K/V from workspace + bit-packed masks (no HBM mask read here at all:
//   one coalesced u64 per thread, per-iteration bytes redistributed via __shfl).
// MODE 1: f16 K/V, masks from global (inline loads in P1).
// MODE 0: no workspace at all (f32 K, scalar V gathers, global masks).
// __launch_bounds__(512,4): 4 waves/EU -> compiler caps regs at 128 -> 2 blocks/CU
// (LDS 70 KB also fits 2). Round-1 lesson: mask reg-prefetch broke this to 1 block/CU.
template <int MODE>
__global__ __launch_bounds__(512, 4) void attn_kernel(
    const float* __restrict__ Q, const float* __restrict__ K,
    const float* __restrict__ V, const _Float16* __restrict__ KH,
    const _Float16* __restrict__ VT, const unsigned char* __restrict__ BITS,
    const int* __restrict__ DM, const int* __restrict__ MMk,
    float* __restrict__ Out, float* __restrict__ Attn)
{
  const int qt    = blockIdx.x;
  const int b     = blockIdx.y;
  const int tid   = (int)threadIdx.x;
  const int w     = tid >> 6;
  const int w4    = w & 3;
  const int hf    = w >> 2;
  const int lane  = tid & 63;
  const int quad  = lane >> 4;
  const int nl    = lane & 15;
  const int row16 = tid >> 5;
  const int ci    = tid & 31;

  const int qbase    = qt * TQ;
  const size_t bLD   = (size_t)b * SL * HD;
  const size_t mbase = ((size_t)b * SL + qbase) * SL;

  __shared__ __align__(16) _Float16 S[TQ * SSTRIDE];
  __shared__ float sinv_s[TQ];
  __shared__ float obuf[TQ][65];

  // ---- mask bits: one u64 per thread covers 64 cols of its row (tid = row16*32+ci)
  unsigned Wlo = 0, Whi = 0;
  if constexpr (MODE == 2) {
    const unsigned long long* browp =
        (const unsigned long long*)BITS + ((size_t)b * SL + qbase) * (SL / 64);
    const unsigned long long Wll = browp[tid];
    Wlo = (unsigned)Wll;
    Whi = (unsigned)(Wll >> 32);
  }

  // ---- Q fragments (A operand): lane holds Q[qbase + nl][quad*8+j (+32)]
  half8 aq0, aq1;
  {
    const float* qp = Q + bLD + (size_t)(qbase + nl) * HD + quad * 8;
    aq0 = load_frag_f32(qp);
    aq1 = load_frag_f32(qp + 32);
  }

  // ================= Phase A: QK^T -> S (each wave: 16 tiles) =================
  const int kt0 = hf * (NT / 2);
  #pragma unroll 2
  for (int kti = 0; kti < NT / 2; ++kti) {
    const int kt = kt0 + kti;
    half8 bk0, bk1;
    if constexpr (MODE >= 1) {
      const _Float16* kp = KH + bLD + (size_t)(kt * BK + w4 * 16 + nl) * HD + quad * 8;
      bk0 = *(const half8*)kp;
      bk1 = *(const half8*)(kp + 32);
    } else {
      const float* kp = K + bLD + (size_t)(kt * BK + w4 * 16 + nl) * HD + quad * 8;
      bk0 = load_frag_f32(kp);
      bk1 = load_frag_f32(kp + 32);
    }
    floatx4 acc = {0.f, 0.f, 0.f, 0.f};
    acc = __builtin_amdgcn_mfma_f32_16x16x32_f16(aq0, bk0, acc, 0, 0, 0);
    acc = __builtin_amdgcn_mfma_f32_16x16x32_f16(aq1, bk1, acc, 0, 0, 0);
    const int col = kt * BK + w4 * 16 + nl;
    #pragma unroll
    for (int r = 0; r < 4; ++r)
      S[(quad * 4 + r) * SSTRIDE + col] = (_Float16)(acc[r] * SC2);
  }
  __syncthreads();

  // ========== P1: mask + exp2 + sum, one in-place pass (no row max) ==========
  _Float16* srow = &S[row16 * SSTRIDE];
  float sum = 0.f;
  if constexpr (MODE == 2) {
    const bool useLo = (ci & 4) == 0;        // byte (ci&7) lives in lo word if <4
    const int  bsh   = (ci & 3) * 8;
    #pragma unroll
    for (int it = 0; it < 8; ++it) {
      const int c    = it * 256 + ci * 8;
      const int srcl = (lane & 32) | (it * 4 + (ci >> 3));
      const unsigned lo = __shfl(Wlo, srcl, 64);
      const unsigned hi = __shfl(Whi, srcl, 64);
      const unsigned kb = ((useLo ? lo : hi) >> bsh) & 0xFFu;
      half8 s8 = *(const half8*)(srow + c);
      half8 e8;
      #pragma unroll
      for (int j = 0; j < 4; ++j) {
        const float e0 = (kb & (1u << j))       ? __builtin_amdgcn_exp2f((float)s8[j])     : 0.f;
        const float e1 = (kb & (1u << (j + 4))) ? __builtin_amdgcn_exp2f((float)s8[j + 4]) : 0.f;
        sum += e0 + e1;
        e8[j]     = (_Float16)e0;   // e <= ~e^6, fp16 safe (validated earlier rounds)
        e8[j + 4] = (_Float16)e1;
      }
      *(half8*)(srow + c) = e8;     // unnormalized e for PV
    }
  } else {
    const int* dmr = DM  + mbase + (size_t)row16 * SL;
    const int* mkr = MMk + mbase + (size_t)row16 * SL;
    #pragma unroll 4
    for (int it = 0; it < 8; ++it) {
      const int c = it * 256 + ci * 8;
      intx4 d0 = __builtin_nontemporal_load((const intx4*)(dmr + c));
      intx4 d1 = __builtin_nontemporal_load((const intx4*)(dmr + c + 4));
      intx4 m0 = __builtin_nontemporal_load((const intx4*)(mkr + c));
      intx4 m1 = __builtin_nontemporal_load((const intx4*)(mkr + c + 4));
      half8 s8 = *(const half8*)(srow + c);
      half8 e8;
      #pragma unroll
      for (int j = 0; j < 4; ++j) {
        const int keep0 = d0[j] & ~m0[j];
        const int keep1 = d1[j] & ~m1[j];
        const float e0 = keep0 ? __builtin_amdgcn_exp2f((float)s8[j])     : 0.f;
        const float e1 = keep1 ? __builtin_amdgcn_exp2f((float)s8[j + 4]) : 0.f;
        sum += e0 + e1;
        e8[j]     = (_Float16)e0;
        e8[j + 4] = (_Float16)e1;
      }
      *(half8*)(srow + c) = e8;
    }
  }
  #pragma unroll
  for (int off = 1; off < 32; off <<= 1)
    sum += __shfl_xor(sum, off, 64);   // 32 chunk-lanes of this row
  const float is = (sum > 0.f) ? 1.f / sum : 0.f;
  if (ci == 0) sinv_s[row16] = is;
  __syncthreads();   // all e in S + sinv_s visible before PV

  // ===== D2: PV MFMA (16 tiles/wave) with interleaved normalized attn stores =====
  const float isr = sinv_s[row16];
  float* arow = Attn + mbase + (size_t)row16 * SL;
  floatx4 oacc = {0.f, 0.f, 0.f, 0.f};
  #pragma unroll
  for (int kti = 0; kti < NT / 2; ++kti) {
    const int kt = kt0 + kti;
    // A operand: lane holds E[m = nl][k = kt*64 + quad*8 + j (+32)]
    half8 ap0 = *(const half8*)(&S[nl * SSTRIDE + kt * BK + quad * 8]);
    half8 ap1 = *(const half8*)(&S[nl * SSTRIDE + kt * BK + quad * 8 + 32]);
    // B operand: lane holds V[k = kt*64 + quad*8 + j (+32)][n = w4*16 + nl]
    half8 bv0, bv1;
    if constexpr (MODE >= 1) {
      const _Float16* vp = VT + bLD + (size_t)(w4 * 16 + nl) * SL + kt * BK + quad * 8;
      bv0 = *(const half8*)vp;
      bv1 = *(const half8*)(vp + 32);
    } else {
      const float* vp = V + bLD + (size_t)(kt * BK + quad * 8) * HD + w4 * 16 + nl;
      #pragma unroll
      for (int j = 0; j < 8; ++j) {
        bv0[j] = (_Float16)vp[(size_t)j * HD];
        bv1[j] = (_Float16)vp[(size_t)(j + 32) * HD];
      }
    }
    oacc = __builtin_amdgcn_mfma_f32_16x16x32_f16(ap0, bv0, oacc, 0, 0, 0);
    oacc = __builtin_amdgcn_mfma_f32_16x16x32_f16(ap1, bv1, oacc, 0, 0, 0);
    // P3 chunk every other tile: stores drain under the MFMA latency
    if ((kti & 1) == 0) {
      const int c = (kti >> 1) * 256 + ci * 8;
      half8 e8v = *(const half8*)(srow + c);
      floatx4 o0, o1;
      #pragma unroll
      for (int j = 0; j < 4; ++j) {
        o0[j] = (float)e8v[j]     * isr;
        o1[j] = (float)e8v[j + 4] * isr;
      }
      __builtin_nontemporal_store(o0, (floatx4*)(arow + c));
      __builtin_nontemporal_store(o1, (floatx4*)(arow + c + 4));
    }
  }

  // ---- merge the two k-halves, normalize, store O
  if (hf == 1) {
    #pragma unroll
    for (int r = 0; r < 4; ++r)
      obuf[quad * 4 + r][w4 * 16 + nl] = oacc[r];
  }
  __syncthreads();
  if (hf == 0) {
    float* op = Out + ((size_t)b * SL + qbase) * HD;
    #pragma unroll
    for (int r = 0; r < 4; ++r) {
      const int row = quad * 4 + r;
      op[(size_t)row * HD + w4 * 16 + nl] =
          (oacc[r] + obuf[row][w4 * 16 + nl]) * sinv_s[row];
    }
  }
}

extern "C" void kernel_launch(void* const* d_in, const int* in_sizes, int n_in,
                              void* d_out, int out_size, void* d_ws, size_t ws_size,
                              hipStream_t stream) {
  const float* Q  = (const float*)d_in[0];
  const float* K  = (const float*)d_in[1];
  const float* V  = (const float*)d_in[2];
  const int* DM   = (const int*)d_in[3];
  const int* MMk  = (const int*)d_in[4];
  float* Out  = (float*)d_out;
  float* Attn = (float*)d_out + (size_t)NB * SL * HD;
  dim3 grid(SL / TQ, NB);

  const size_t needKV   = (size_t)2 * NB * SL * HD * sizeof(_Float16);  // 8 MiB
  const size_t needBits = (size_t)NB * SL * (SL / 8);                   // 8 MiB
  if (d_ws != nullptr && ws_size >= needKV + needBits) {
    _Float16* KH = (_Float16*)d_ws;
    _Float16* VT = KH + (size_t)NB * SL * HD;
    unsigned char* BITS = (unsigned char*)(VT + (size_t)NB * SL * HD);
    prep_pack_kernel<<<dim3(2048 + 512), 256, 0, stream>>>(K, V, DM, MMk, KH, VT, BITS);
    attn_kernel<2><<<grid, 512, 0, stream>>>(Q, K, V, KH, VT, BITS, DM, MMk, Out, Attn);
  } else if (d_ws != nullptr && ws_size >= needKV) {
    _Float16* KH = (_Float16*)d_ws;
    _Float16* VT = KH + (size_t)NB * SL * HD;
    prep_pack_kernel<<<dim3(512), 256, 0, stream>>>(K, V, DM, MMk, KH, VT, nullptr); // prep only? (bid<2048 skipped)
    attn_kernel<1><<<grid, 512, 0, stream>>>(Q, K, V, KH, VT, nullptr, DM, MMk, Out, Attn);
  } else {
    attn_kernel<0><<<grid, 512, 0, stream>>>(Q, K, V, nullptr, nullptr, nullptr, DM, MMk, Out, Attn);
  }
}